// Round 4
// baseline (318.242 us; speedup 1.0000x reference)
//
#include <hip/hip_runtime.h>

// LightGCN on MI355X — round 9:
//  * compact bucket-local CSR: phaseB prefix-scans padded degs -> od[n]={off,deg};
//    slot footprint 24MB -> 9.6MB (saves ~10MB fetch per gather + ~30MB phaseB RFO/WB).
//  * gather: 4 nodes per wave -> 2x MLP vs round 8; slot quads via per-lane-group
//    int2 vector load (edges c+2j,c+2j+1) -> no cndmask selects.
//  * sentinel-row zeroing folded into phaseB; 2 memsets dropped.

#define NU 100000
#define NI 50000
#define NN 150000
#define QUARTER 37500
#define DIM 64
#define NE 1250000
#define NF (NN * DIM)
#define NF4 (NF / 4)
#define NBK 293                      // ceil(NN/512) coarse buckets of 512 nodes
#define BSTRIDE 5120                 // part entries per bucket (mean 4267, +13 sigma)
#define BSLOT 8192                   // slot ints per bucket (mean ~6093, +21 sigma)
#define PB 256                       // phase-A partition blocks
#define EPB ((NE + PB - 1) / PB)     // 4883 edges per partition block

typedef unsigned short ushort_t;

__device__ inline ushort_t f2bf(float f) {          // RNE float -> bf16
    unsigned u = __float_as_uint(f);
    return (ushort_t)((u + 0x7FFF + ((u >> 16) & 1)) >> 16);
}
__device__ inline float bflo(unsigned u) { return __uint_as_float(u << 16); }
__device__ inline float bfhi(unsigned u) { return __uint_as_float(u & 0xffff0000u); }

// ---- phase A: partition edges into coarse dst-buckets; packed 4B entries ----
__global__ void __launch_bounds__(1024) phaseA_kernel(const int* __restrict__ src,
                                                      const int* __restrict__ dst,
                                                      int* __restrict__ bcursor,
                                                      int* __restrict__ part) {
    __shared__ int hist[NBK];
    __shared__ int cur[NBK];
    int b = blockIdx.x;
    int tid = threadIdx.x;
    if (tid < NBK) hist[tid] = 0;
    __syncthreads();
    int e0 = b * EPB;
    int e1 = min(e0 + EPB, NE);
    for (int e = e0 + tid; e < e1; e += 1024)
        atomicAdd(&hist[dst[e] >> 9], 1);
    __syncthreads();
    if (tid < NBK) {
        int h = hist[tid];
        int base = h ? atomicAdd(&bcursor[tid], h) : 0;   // reserve run in bucket
        cur[tid] = tid * BSTRIDE + base;
    }
    __syncthreads();
    for (int e = e0 + tid; e < e1; e += 1024) {
        int dd = dst[e];
        int s = src[e];
        int p = atomicAdd(&cur[dd >> 9], 1);              // LDS atomic
        part[p] = ((dd & 511) << 18) | s;                 // dloc:9 | src:18
    }
}

// ---- phase B: compact CSR build + deg/rdeg + pre-scaled bf16 rows ----
__global__ void __launch_bounds__(1024) phaseB_kernel(const int* __restrict__ bcursor,
                                                      const int* __restrict__ part,
                                                      int2* __restrict__ od,
                                                      float* __restrict__ rdeg,
                                                      int* __restrict__ slots,
                                                      const float4* __restrict__ uw4,
                                                      const float4* __restrict__ iw4,
                                                      ushort_t* __restrict__ embb,
                                                      ushort_t* __restrict__ bufT) {
    __shared__ int stash[BSTRIDE];                        // 20.5 KB edge stash
    __shared__ int dcount[512];
    __shared__ int cnt2[512];
    __shared__ int sc[512];                               // scan array
    __shared__ int offL[512];
    __shared__ float rfs[512];
    int b = blockIdx.x;
    int tid = threadIdx.x;
    int cnt = min(bcursor[b], BSTRIDE);
    int nodebase = b * 512;
    if (tid < 512) dcount[tid] = 0;
    if (b == 0 && tid < DIM) {                            // sentinel row NN = 0
        embb[NF + tid] = 0;
        bufT[NF + tid] = 0;
    }
    __syncthreads();
    // pass 1: stash part in LDS + per-node count
    const int* pb = part + b * BSTRIDE;
    for (int i = tid; i < cnt; i += 1024) {
        int v = pb[i];                                    // coalesced read
        stash[i] = v;
        atomicAdd(&dcount[v >> 18], 1);                   // LDS atomic
    }
    __syncthreads();
    if (tid < 512) {
        int c = dcount[tid];
        int pad = (c <= 8) ? 8 : ((c + 7) & ~7);          // pad to >=8, mult of 8
        sc[tid] = pad;
        int n = nodebase + tid;
        float r = 0.0f;
        if (n < NN) {
            r = (c > 0) ? rsqrtf((float)c) : 0.0f;
            rdeg[n] = r;
        }
        rfs[tid] = r;
    }
    __syncthreads();
    // inclusive scan of padded degs over 512 entries
    for (int ofs = 1; ofs < 512; ofs <<= 1) {
        int v = 0;
        if (tid < 512 && tid >= ofs) v = sc[tid - ofs];
        __syncthreads();
        if (tid < 512 && tid >= ofs) sc[tid] += v;
        __syncthreads();
    }
    if (tid < 512) {
        int c = dcount[tid];
        int pad = (c <= 8) ? 8 : ((c + 7) & ~7);
        int off = b * BSLOT + sc[tid] - pad;              // exclusive offset
        offL[tid] = off;
        cnt2[tid] = 0;
        int n = nodebase + tid;
        if (n < NN) {
            od[n] = make_int2(off, c);
            for (int k = c; k < pad; k++)
                slots[off + k] = NN;                      // sentinel (zero row)
        }
    }
    __syncthreads();
    // pass 2: placement from stash into compact slots
    for (int i = tid; i < cnt; i += 1024) {
        int v = stash[i];
        int dloc = v >> 18;
        int p = atomicAdd(&cnt2[dloc], 1);                // LDS atomic
        slots[offL[dloc] + p] = v & 0x3FFFF;
    }
    // pass 3: p0 = bf16(emb_f32 * rdeg) — single rounding (indep of pass 2)
    int nnode = min(512, NN - nodebase);
    int lim = nnode * 16;                                 // float4 per node = 16
    for (int q = tid; q < lim; q += 1024) {
        int nl = q >> 4;
        int node = nodebase + nl;
        int c4 = q & 15;
        float4 v = (node < NU) ? uw4[node * 16 + c4] : iw4[(node - NU) * 16 + c4];
        float r = rfs[nl];
        ushort4 h;
        h.x = f2bf(v.x * r); h.y = f2bf(v.y * r);
        h.z = f2bf(v.z * r); h.w = f2bf(v.w * r);
        *(ushort4*)(embb + node * DIM + c4 * 4) = h;
    }
}

// ---- gather: wave handles 4 nodes (n, n+37.5K, +75K, +112.5K) ----
// lane group j (=lane>>4) takes edges c+2j,c+2j+1 via one int2 load; d=lane&15.
// rows pre-scaled by rdeg[src]; sentinel rows zero; out = rd * sum(p[src]).
template <int LAYER>
__global__ void __launch_bounds__(1024) gather_kernel(const int2* __restrict__ od,
                                                      const float* __restrict__ rdeg,
                                                      const int* __restrict__ slots,
                                                      const ushort_t* __restrict__ cur,
                                                      const float4* __restrict__ uw4,
                                                      const float4* __restrict__ iw4,
                                                      float4* __restrict__ acc,
                                                      ushort_t* __restrict__ nxt) {
    int wid = blockIdx.x * 16 + (threadIdx.x >> 6);
    int n0 = __builtin_amdgcn_readfirstlane(wid);
    if (n0 >= QUARTER) return;
    int n1 = n0 + QUARTER;
    int n2 = n0 + 2 * QUARTER;
    int n3 = n0 + 3 * QUARTER;
    int lane = threadIdx.x & 63;
    int j2 = (lane >> 3) & ~1;                        // 2*j, j = lane>>4
    int d = lane & 15;                                // dim quad (dims 4d..4d+3)

    int2 v0 = od[n0];
    int2 v1 = od[n1];
    int2 v2 = od[n2];
    int2 v3 = od[n3];
    int of0 = __builtin_amdgcn_readfirstlane(v0.x);
    int dg0 = __builtin_amdgcn_readfirstlane(v0.y);
    int of1 = __builtin_amdgcn_readfirstlane(v1.x);
    int dg1 = __builtin_amdgcn_readfirstlane(v1.y);
    int of2 = __builtin_amdgcn_readfirstlane(v2.x);
    int dg2 = __builtin_amdgcn_readfirstlane(v2.y);
    int of3 = __builtin_amdgcn_readfirstlane(v3.x);
    int dg3 = __builtin_amdgcn_readfirstlane(v3.y);
    float rd0 = __uint_as_float(__builtin_amdgcn_readfirstlane(__float_as_uint(rdeg[n0])));
    float rd1 = __uint_as_float(__builtin_amdgcn_readfirstlane(__float_as_uint(rdeg[n1])));
    float rd2 = __uint_as_float(__builtin_amdgcn_readfirstlane(__float_as_uint(rdeg[n2])));
    float rd3 = __uint_as_float(__builtin_amdgcn_readfirstlane(__float_as_uint(rdeg[n3])));
    const int* sb0 = slots + of0;
    const int* sb1 = slots + of1;
    const int* sb2 = slots + of2;
    const int* sb3 = slots + of3;
    float x0 = 0, x1 = 0, x2 = 0, x3 = 0;
    float y0 = 0, y1 = 0, y2 = 0, y3 = 0;
    float z0 = 0, z1 = 0, z2 = 0, z3 = 0;
    float w0 = 0, w1 = 0, w2 = 0, w3 = 0;

#define GRP(SB, C, X0, X1, X2, X3)                                             \
    {                                                                          \
        int2 sv = *(const int2*)((SB) + (C) + j2);                             \
        uint2 ua = *((const uint2*)(cur + sv.x * DIM) + d);                    \
        uint2 ub = *((const uint2*)(cur + sv.y * DIM) + d);                    \
        X0 += bflo(ua.x); X1 += bfhi(ua.x);                                    \
        X2 += bflo(ua.y); X3 += bfhi(ua.y);                                    \
        X0 += bflo(ub.x); X1 += bfhi(ub.x);                                    \
        X2 += bflo(ub.y); X3 += bfhi(ub.y);                                    \
    }

    GRP(sb0, 0, x0, x1, x2, x3)                       // unconditional (pad>=8)
    GRP(sb1, 0, y0, y1, y2, y3)
    GRP(sb2, 0, z0, z1, z2, z3)
    GRP(sb3, 0, w0, w1, w2, w3)
    for (int c = 8; c < dg0; c += 8) GRP(sb0, c, x0, x1, x2, x3)
    for (int c = 8; c < dg1; c += 8) GRP(sb1, c, y0, y1, y2, y3)
    for (int c = 8; c < dg2; c += 8) GRP(sb2, c, z0, z1, z2, z3)
    for (int c = 8; c < dg3; c += 8) GRP(sb3, c, w0, w1, w2, w3)
#undef GRP

    // reduce across the 4 j-groups (butterfly xor16, xor32)
    x0 += __shfl_xor(x0, 16); x1 += __shfl_xor(x1, 16);
    x2 += __shfl_xor(x2, 16); x3 += __shfl_xor(x3, 16);
    y0 += __shfl_xor(y0, 16); y1 += __shfl_xor(y1, 16);
    y2 += __shfl_xor(y2, 16); y3 += __shfl_xor(y3, 16);
    z0 += __shfl_xor(z0, 16); z1 += __shfl_xor(z1, 16);
    z2 += __shfl_xor(z2, 16); z3 += __shfl_xor(z3, 16);
    w0 += __shfl_xor(w0, 16); w1 += __shfl_xor(w1, 16);
    w2 += __shfl_xor(w2, 16); w3 += __shfl_xor(w3, 16);
    x0 += __shfl_xor(x0, 32); x1 += __shfl_xor(x1, 32);
    x2 += __shfl_xor(x2, 32); x3 += __shfl_xor(x3, 32);
    y0 += __shfl_xor(y0, 32); y1 += __shfl_xor(y1, 32);
    y2 += __shfl_xor(y2, 32); y3 += __shfl_xor(y3, 32);
    z0 += __shfl_xor(z0, 32); z1 += __shfl_xor(z1, 32);
    z2 += __shfl_xor(z2, 32); z3 += __shfl_xor(z3, 32);
    w0 += __shfl_xor(w0, 32); w1 += __shfl_xor(w1, 32);
    w2 += __shfl_xor(w2, 32); w3 += __shfl_xor(w3, 32);

    if ((lane >> 4) != 0) return;                     // 16 lanes do the epilogue

#define EPI(N, RD, A0, A1, A2, A3, EMB)                                        \
    {                                                                          \
        float c0 = (RD) * (A0), c1 = (RD) * (A1);                              \
        float c2 = (RD) * (A2), c3 = (RD) * (A3);                              \
        int i4 = (N) * 16 + d;                                                 \
        if (LAYER == 1) {                                                      \
            float4 e = (EMB);                                                  \
            acc[i4] = make_float4(e.x + c0, e.y + c1, e.z + c2, e.w + c3);     \
            ushort4 h;                                                         \
            h.x = f2bf((RD) * c0); h.y = f2bf((RD) * c1);                      \
            h.z = f2bf((RD) * c2); h.w = f2bf((RD) * c3);                      \
            *(ushort4*)(nxt + (N) * DIM + d * 4) = h;                          \
        } else if (LAYER == 2) {                                               \
            float4 t = acc[i4];                                                \
            acc[i4] = make_float4(t.x + c0, t.y + c1, t.z + c2, t.w + c3);     \
            ushort4 h;                                                         \
            h.x = f2bf((RD) * c0); h.y = f2bf((RD) * c1);                      \
            h.z = f2bf((RD) * c2); h.w = f2bf((RD) * c3);                      \
            *(ushort4*)(nxt + (N) * DIM + d * 4) = h;                          \
        } else {                                                               \
            float4 t = acc[i4];                                                \
            float4 v = make_float4((t.x + c0) * 0.25f, (t.y + c1) * 0.25f,     \
                                   (t.z + c2) * 0.25f, (t.w + c3) * 0.25f);    \
            acc[i4] = v;                                                       \
            acc[NF4 + i4] = v;                                                 \
        }                                                                      \
    }

    // n0,n1 < 75000 -> uw; n2 in [75000,112500) -> branch; n3 >= 112500 -> iw
    EPI(n0, rd0, x0, x1, x2, x3, uw4[n0 * 16 + d])
    EPI(n1, rd1, y0, y1, y2, y3, uw4[n1 * 16 + d])
    EPI(n2, rd2, z0, z1, z2, z3,
        ((n2 < NU) ? uw4[n2 * 16 + d] : iw4[(n2 - NU) * 16 + d]))
    EPI(n3, rd3, w0, w1, w2, w3, iw4[(n3 - NU) * 16 + d])
#undef EPI
}

extern "C" void kernel_launch(void* const* d_in, const int* in_sizes, int n_in,
                              void* d_out, int out_size, void* d_ws, size_t ws_size,
                              hipStream_t stream) {
    const int* edge = (const int*)d_in[0];
    const int* src = edge;
    const int* dst = edge + NE;
    const float* uw = (const float*)d_in[1];
    const float* iw = (const float*)d_in[2];
    float* out = (float*)d_out;

    // workspace layout (16B-aligned chunks), ~36.6 MB total
    int2* od       = (int2*)d_ws;                    // NN int2 {off,deg} (1.2 MB)
    float* rdeg    = (float*)(od + NN);              // NN floats
    int* bcursor   = (int*)(rdeg + NN);              // NBK ints (+pad to 16B)
    int* slots     = bcursor + 320;                  // NBK*BSLOT ints (9.6 MB)
    int* part      = slots + NBK * BSLOT;            // NBK*BSTRIDE ints (6 MB)
    ushort_t* embb = (ushort_t*)(part + NBK * BSTRIDE); // (NF+DIM) bf16: p0 + zero row
    ushort_t* bufA = embb;                           // alias: embb dead after L1
    ushort_t* bufT = (ushort_t*)(out + NF);          // out tail: p1 home (+ zero row)

    hipMemsetAsync(bcursor, 0, NBK * sizeof(int), stream);

    phaseA_kernel<<<PB, 1024, 0, stream>>>(src, dst, bcursor, part);
    phaseB_kernel<<<NBK, 1024, 0, stream>>>(bcursor, part, od, rdeg, slots,
                                            (const float4*)uw, (const float4*)iw,
                                            embb, bufT);

    const int GB = (QUARTER + 15) / 16;              // 2344 blocks of 16 waves

    // L1: cur = p0 (embb), acc = emb + x1 -> out[0:NF], p1 -> bufT
    gather_kernel<1><<<GB, 1024, 0, stream>>>(od, rdeg, slots, embb,
                                              (const float4*)uw, (const float4*)iw,
                                              (float4*)out, bufT);
    // L2: cur = p1 (bufT), acc += x2, p2 -> bufA (= embb, dead after L1)
    gather_kernel<2><<<GB, 1024, 0, stream>>>(od, rdeg, slots, bufT,
                                              (const float4*)uw, (const float4*)iw,
                                              (float4*)out, bufA);
    // L3: cur = p2 (bufA), writes (acc+x3)/4 to both output halves
    gather_kernel<3><<<GB, 1024, 0, stream>>>(od, rdeg, slots, bufA,
                                              (const float4*)uw, (const float4*)iw,
                                              (float4*)out, nullptr);
}

// Round 5
// 307.193 us; speedup vs baseline: 1.0360x; 1.0360x over previous
//
#include <hip/hip_runtime.h>

// LightGCN on MI355X — round 10:
//  * gather reverted to round-8 2-node/wave structure (proven 45us @ 104MB —
//    saturates the ~2.4 TB/s L2-fill path; round 9's 4-node version added
//    +53MB fetch and time scaled with bytes).
//  * keep round-9 compact bucket-local CSR (slot lines 14.4 -> ~6.8 MB/gather).
//  * od packed to ONE uint {deg:6 | off:26}; rdeg array deleted — gather and
//    phaseB both compute rsqrtf((float)deg) (bit-identical prescale factor).

#define NU 100000
#define NI 50000
#define NN 150000
#define HALF 75000
#define DIM 64
#define NE 1250000
#define NF (NN * DIM)
#define NF4 (NF / 4)
#define NBK 293                      // ceil(NN/512) coarse buckets of 512 nodes
#define BSTRIDE 5120                 // part entries per bucket (mean 4267, +13 sigma)
#define BSLOT 8192                   // slot ints per bucket (proven fit in round 9)
#define PB 256                       // phase-A partition blocks
#define EPB ((NE + PB - 1) / PB)     // 4883 edges per partition block

typedef unsigned short ushort_t;

__device__ inline ushort_t f2bf(float f) {          // RNE float -> bf16
    unsigned u = __float_as_uint(f);
    return (ushort_t)((u + 0x7FFF + ((u >> 16) & 1)) >> 16);
}
__device__ inline float bflo(unsigned u) { return __uint_as_float(u << 16); }
__device__ inline float bfhi(unsigned u) { return __uint_as_float(u & 0xffff0000u); }

// ---- phase A: partition edges into coarse dst-buckets; packed 4B entries ----
__global__ void __launch_bounds__(1024) phaseA_kernel(const int* __restrict__ src,
                                                      const int* __restrict__ dst,
                                                      int* __restrict__ bcursor,
                                                      int* __restrict__ part) {
    __shared__ int hist[NBK];
    __shared__ int cur[NBK];
    int b = blockIdx.x;
    int tid = threadIdx.x;
    if (tid < NBK) hist[tid] = 0;
    __syncthreads();
    int e0 = b * EPB;
    int e1 = min(e0 + EPB, NE);
    for (int e = e0 + tid; e < e1; e += 1024)
        atomicAdd(&hist[dst[e] >> 9], 1);
    __syncthreads();
    if (tid < NBK) {
        int h = hist[tid];
        int base = h ? atomicAdd(&bcursor[tid], h) : 0;   // reserve run in bucket
        cur[tid] = tid * BSTRIDE + base;
    }
    __syncthreads();
    for (int e = e0 + tid; e < e1; e += 1024) {
        int dd = dst[e];
        int s = src[e];
        int p = atomicAdd(&cur[dd >> 9], 1);              // LDS atomic
        part[p] = ((dd & 511) << 18) | s;                 // dloc:9 | src:18
    }
}

// ---- phase B: compact CSR build + packed od + pre-scaled bf16 rows ----
__global__ void __launch_bounds__(1024) phaseB_kernel(const int* __restrict__ bcursor,
                                                      const int* __restrict__ part,
                                                      unsigned* __restrict__ od,
                                                      int* __restrict__ slots,
                                                      const float4* __restrict__ uw4,
                                                      const float4* __restrict__ iw4,
                                                      ushort_t* __restrict__ embb,
                                                      ushort_t* __restrict__ bufT) {
    __shared__ int stash[BSTRIDE];                        // 20.5 KB edge stash
    __shared__ int dcount[512];
    __shared__ int cnt2[512];
    __shared__ int sc[512];                               // scan array
    __shared__ int offL[512];
    __shared__ float rfs[512];
    int b = blockIdx.x;
    int tid = threadIdx.x;
    int cnt = min(bcursor[b], BSTRIDE);
    int nodebase = b * 512;
    if (tid < 512) dcount[tid] = 0;
    if (b == 0 && tid < DIM) {                            // sentinel row NN = 0
        embb[NF + tid] = 0;
        bufT[NF + tid] = 0;
    }
    __syncthreads();
    // pass 1: stash part in LDS + per-node count
    const int* pb = part + b * BSTRIDE;
    for (int i = tid; i < cnt; i += 1024) {
        int v = pb[i];                                    // coalesced read
        stash[i] = v;
        atomicAdd(&dcount[v >> 18], 1);                   // LDS atomic
    }
    __syncthreads();
    if (tid < 512) {
        int c = dcount[tid];
        int pad = (c <= 8) ? 8 : ((c + 7) & ~7);          // pad to >=8, mult of 8
        sc[tid] = pad;
        rfs[tid] = (c > 0) ? rsqrtf((float)c) : 0.0f;
    }
    __syncthreads();
    // inclusive scan of padded degs over 512 entries
    for (int ofs = 1; ofs < 512; ofs <<= 1) {
        int v = 0;
        if (tid < 512 && tid >= ofs) v = sc[tid - ofs];
        __syncthreads();
        if (tid < 512 && tid >= ofs) sc[tid] += v;
        __syncthreads();
    }
    if (tid < 512) {
        int c = dcount[tid];
        int pad = (c <= 8) ? 8 : ((c + 7) & ~7);
        int off = b * BSLOT + sc[tid] - pad;              // exclusive offset
        offL[tid] = off;
        cnt2[tid] = 0;
        int n = nodebase + tid;
        if (n < NN) {
            od[n] = (unsigned)off | ((unsigned)c << 26);  // deg:6 | off:26
            for (int k = c; k < pad; k++)
                slots[off + k] = NN;                      // sentinel (zero row)
        }
    }
    __syncthreads();
    // pass 2: placement from stash into compact slots
    for (int i = tid; i < cnt; i += 1024) {
        int v = stash[i];
        int dloc = v >> 18;
        int p = atomicAdd(&cnt2[dloc], 1);                // LDS atomic
        slots[offL[dloc] + p] = v & 0x3FFFF;
    }
    // pass 3: p0 = bf16(emb_f32 * rdeg) — single rounding (indep of pass 2)
    int nnode = min(512, NN - nodebase);
    int lim = nnode * 16;                                 // float4 per node = 16
    for (int q = tid; q < lim; q += 1024) {
        int nl = q >> 4;
        int node = nodebase + nl;
        int c4 = q & 15;
        float4 v = (node < NU) ? uw4[node * 16 + c4] : iw4[(node - NU) * 16 + c4];
        float r = rfs[nl];
        ushort4 h;
        h.x = f2bf(v.x * r); h.y = f2bf(v.y * r);
        h.z = f2bf(v.z * r); h.w = f2bf(v.w * r);
        *(ushort4*)(embb + node * DIM + c4 * 4) = h;
    }
}

// ---- gather: wave handles 2 nodes (n, n+75000); lane j=edge-slot, d=dim-quad ----
// rows pre-scaled by rdeg[src]; sentinel rows are zero; out c = rd * sum(p[src]).
template <int LAYER>
__global__ void __launch_bounds__(1024) gather_kernel(const unsigned* __restrict__ od,
                                                      const int* __restrict__ slots,
                                                      const ushort_t* __restrict__ cur,
                                                      const float4* __restrict__ uw4,
                                                      const float4* __restrict__ iw4,
                                                      float4* __restrict__ acc,
                                                      ushort_t* __restrict__ nxt) {
    int wid = blockIdx.x * 16 + (threadIdx.x >> 6);
    int n0 = __builtin_amdgcn_readfirstlane(wid);
    if (n0 >= HALF) return;
    int n1 = n0 + HALF;
    int lane = threadIdx.x & 63;
    int j = lane >> 4;                                // edge sub-slot 0..3
    int d = lane & 15;                                // dim quad (dims 4d..4d+3)
    bool j1 = (j & 1) != 0;
    bool j2 = (j & 2) != 0;
    unsigned v0 = (unsigned)__builtin_amdgcn_readfirstlane((int)od[n0]);
    unsigned v1 = (unsigned)__builtin_amdgcn_readfirstlane((int)od[n1]);
    int of0 = (int)(v0 & 0x3FFFFFFu);
    int dg0 = (int)(v0 >> 26);
    int of1 = (int)(v1 & 0x3FFFFFFu);
    int dg1 = (int)(v1 >> 26);
    float rd0 = (dg0 > 0) ? rsqrtf((float)dg0) : 0.0f;   // == phaseB's factor
    float rd1 = (dg1 > 0) ? rsqrtf((float)dg1) : 0.0f;
    const int* sb0 = slots + of0;
    const int* sb1 = slots + of1;
    float a0 = 0, a1 = 0, a2 = 0, a3 = 0;
    float b0 = 0, b1 = 0, b2 = 0, b3 = 0;

#define GRP(SB, C, X0, X1, X2, X3)                                             \
    {                                                                          \
        int4 qa = *(const int4*)((SB) + (C));                                  \
        int4 qb = *(const int4*)((SB) + (C) + 4);                              \
        int ta = j1 ? qa.y : qa.x;                                             \
        int tb = j1 ? qa.w : qa.z;                                             \
        int sva = j2 ? tb : ta;                                                \
        int tc = j1 ? qb.y : qb.x;                                             \
        int td = j1 ? qb.w : qb.z;                                             \
        int svb = j2 ? td : tc;                                                \
        uint2 ua = *((const uint2*)(cur + sva * DIM) + d);                     \
        uint2 ub = *((const uint2*)(cur + svb * DIM) + d);                     \
        X0 += bflo(ua.x); X1 += bfhi(ua.x);                                    \
        X2 += bflo(ua.y); X3 += bfhi(ua.y);                                    \
        X0 += bflo(ub.x); X1 += bfhi(ub.x);                                    \
        X2 += bflo(ub.y); X3 += bfhi(ub.y);                                    \
    }

    GRP(sb0, 0, a0, a1, a2, a3)                       // unconditional (pad>=8)
    GRP(sb1, 0, b0, b1, b2, b3)                       // fully interleaved start
    for (int c = 8; c < dg0; c += 8) GRP(sb0, c, a0, a1, a2, a3)
    for (int c = 8; c < dg1; c += 8) GRP(sb1, c, b0, b1, b2, b3)
#undef GRP

    // reduce across the 4 j-groups (butterfly xor16, xor32)
    a0 += __shfl_xor(a0, 16); a1 += __shfl_xor(a1, 16);
    a2 += __shfl_xor(a2, 16); a3 += __shfl_xor(a3, 16);
    b0 += __shfl_xor(b0, 16); b1 += __shfl_xor(b1, 16);
    b2 += __shfl_xor(b2, 16); b3 += __shfl_xor(b3, 16);
    a0 += __shfl_xor(a0, 32); a1 += __shfl_xor(a1, 32);
    a2 += __shfl_xor(a2, 32); a3 += __shfl_xor(a3, 32);
    b0 += __shfl_xor(b0, 32); b1 += __shfl_xor(b1, 32);
    b2 += __shfl_xor(b2, 32); b3 += __shfl_xor(b3, 32);

    float c00 = rd0 * a0, c01 = rd0 * a1, c02 = rd0 * a2, c03 = rd0 * a3;
    float c10 = rd1 * b0, c11 = rd1 * b1, c12 = rd1 * b2, c13 = rd1 * b3;

    if (j == 0) {                                     // 16 lanes: 256B stores
        int i0 = n0 * 16 + d;
        int i1 = n1 * 16 + d;
        if (LAYER == 1) {
            float4 e0 = uw4[n0 * 16 + d];             // n0 < 75000 < NU always
            float4 e1 = (n1 < NU) ? uw4[n1 * 16 + d] : iw4[(n1 - NU) * 16 + d];
            acc[i0] = make_float4(e0.x + c00, e0.y + c01, e0.z + c02, e0.w + c03);
            acc[i1] = make_float4(e1.x + c10, e1.y + c11, e1.z + c12, e1.w + c13);
            ushort4 h0, h1;
            h0.x = f2bf(rd0 * c00); h0.y = f2bf(rd0 * c01);
            h0.z = f2bf(rd0 * c02); h0.w = f2bf(rd0 * c03);
            h1.x = f2bf(rd1 * c10); h1.y = f2bf(rd1 * c11);
            h1.z = f2bf(rd1 * c12); h1.w = f2bf(rd1 * c13);
            *(ushort4*)(nxt + n0 * DIM + d * 4) = h0; // p1 = bf16(x1 * rdeg)
            *(ushort4*)(nxt + n1 * DIM + d * 4) = h1;
        } else if (LAYER == 2) {
            float4 t0 = acc[i0];
            float4 t1 = acc[i1];
            acc[i0] = make_float4(t0.x + c00, t0.y + c01, t0.z + c02, t0.w + c03);
            acc[i1] = make_float4(t1.x + c10, t1.y + c11, t1.z + c12, t1.w + c13);
            ushort4 h0, h1;
            h0.x = f2bf(rd0 * c00); h0.y = f2bf(rd0 * c01);
            h0.z = f2bf(rd0 * c02); h0.w = f2bf(rd0 * c03);
            h1.x = f2bf(rd1 * c10); h1.y = f2bf(rd1 * c11);
            h1.z = f2bf(rd1 * c12); h1.w = f2bf(rd1 * c13);
            *(ushort4*)(nxt + n0 * DIM + d * 4) = h0; // p2
            *(ushort4*)(nxt + n1 * DIM + d * 4) = h1;
        } else {
            float4 t0 = acc[i0];
            float4 t1 = acc[i1];
            float4 v0 = make_float4((t0.x + c00) * 0.25f, (t0.y + c01) * 0.25f,
                                    (t0.z + c02) * 0.25f, (t0.w + c03) * 0.25f);
            float4 v1 = make_float4((t1.x + c10) * 0.25f, (t1.y + c11) * 0.25f,
                                    (t1.z + c12) * 0.25f, (t1.w + c13) * 0.25f);
            acc[i0] = v0;
            acc[NF4 + i0] = v0;
            acc[i1] = v1;
            acc[NF4 + i1] = v1;
        }
    }
}

extern "C" void kernel_launch(void* const* d_in, const int* in_sizes, int n_in,
                              void* d_out, int out_size, void* d_ws, size_t ws_size,
                              hipStream_t stream) {
    const int* edge = (const int*)d_in[0];
    const int* src = edge;
    const int* dst = edge + NE;
    const float* uw = (const float*)d_in[1];
    const float* iw = (const float*)d_in[2];
    float* out = (float*)d_out;

    // workspace layout (16B-aligned chunks), ~35.4 MB total
    unsigned* od   = (unsigned*)d_ws;                // NN packed {deg:6|off:26} (0.6 MB)
    int* bcursor   = (int*)(od + NN);                // NBK ints (+pad to 16B)
    int* slots     = bcursor + 320;                  // NBK*BSLOT ints (9.6 MB)
    int* part      = slots + NBK * BSLOT;            // NBK*BSTRIDE ints (6 MB)
    ushort_t* embb = (ushort_t*)(part + NBK * BSTRIDE); // (NF+DIM) bf16: p0 + zero row
    ushort_t* bufA = embb;                           // alias: embb dead after L1
    ushort_t* bufT = (ushort_t*)(out + NF);          // out tail: p1 home (+ zero row)

    hipMemsetAsync(bcursor, 0, NBK * sizeof(int), stream);

    phaseA_kernel<<<PB, 1024, 0, stream>>>(src, dst, bcursor, part);
    phaseB_kernel<<<NBK, 1024, 0, stream>>>(bcursor, part, od, slots,
                                            (const float4*)uw, (const float4*)iw,
                                            embb, bufT);

    const int GB = (HALF + 15) / 16;                 // 4688 blocks of 16 waves

    // L1: cur = p0 (embb), acc = emb + x1 -> out[0:NF], p1 -> bufT
    gather_kernel<1><<<GB, 1024, 0, stream>>>(od, slots, embb,
                                              (const float4*)uw, (const float4*)iw,
                                              (float4*)out, bufT);
    // L2: cur = p1 (bufT), acc += x2, p2 -> bufA (= embb, dead after L1)
    gather_kernel<2><<<GB, 1024, 0, stream>>>(od, slots, bufT,
                                              (const float4*)uw, (const float4*)iw,
                                              (float4*)out, bufA);
    // L3: cur = p2 (bufA), writes (acc+x3)/4 to both output halves
    gather_kernel<3><<<GB, 1024, 0, stream>>>(od, slots, bufA,
                                              (const float4*)uw, (const float4*)iw,
                                              (float4*)out, nullptr);
}